// Round 1
// baseline (714.493 us; speedup 1.0000x reference)
//
#include <hip/hip_runtime.h>
#include <hip/hip_bf16.h>
#include <math.h>

#define S_TOT 20000
#define Q_TOT 32
#define N_TOT 200000
#define T_MAX 30
#define G_TOT 64
#define D_IN 300
#define H_DIM 256
#define D_SV 64
#define D_LANG 64
#define D_FUSE 128
#define D_CAT 67          // D_SV + 3
#define FW_LD 131         // fuse_w leading dim (D_SV+3+D_LANG)
#define SCHUNK 32
#define NBLK3 (S_TOT / SCHUNK)   // 625

__device__ __forceinline__ float dot4(float4 a, float4 b) {
    return a.x*b.x + a.y*b.y + a.z*b.z + a.w*b.w;
}
__device__ __forceinline__ float sigmoidf_(float x) { return 1.0f / (1.0f + expf(-x)); }

// ---------------------------------------------------------------- gi = x @ W_ih^T + b_ih
// grid: 32 q * 32 jslices ; block 768 ; each thread one (t, j) dot of length 300
__global__ __launch_bounds__(768) void k_gi(const float* __restrict__ lang_feat,
                                            const float* __restrict__ w_ih,
                                            const float* __restrict__ b_ih,
                                            float* __restrict__ gi) {
    __shared__ __align__(16) float x_l[T_MAX * D_IN];   // 36 KB
    const int q = blockIdx.x >> 5, jsl = blockIdx.x & 31;
    const int tid = threadIdx.x;
    for (int i = tid; i < T_MAX * D_IN; i += 768)
        x_l[i] = lang_feat[q * (T_MAX * D_IN) + i];
    __syncthreads();
    const int t = tid / 24, jl = tid % 24;
    if (t < T_MAX) {
        const int j = jsl * 24 + jl;
        const float4* w4 = (const float4*)(w_ih + j * D_IN);
        const float4* x4 = (const float4*)(x_l + t * D_IN);
        float a0 = 0.f, a1 = 0.f, a2 = 0.f;
        #pragma unroll
        for (int i = 0; i < 75; i += 3) {
            a0 += dot4(w4[i],   x4[i]);
            a1 += dot4(w4[i+1], x4[i+1]);
            a2 += dot4(w4[i+2], x4[i+2]);
        }
        gi[(q * T_MAX + t) * 768 + j] = b_ih[j] + a0 + a1 + a2;
    }
}

// ---------------------------------------------------------------- sequential GRU, one block per query
__global__ __launch_bounds__(768) void k_gru(const float* __restrict__ gi,
                                             const float* __restrict__ w_hh,
                                             const float* __restrict__ b_hh,
                                             const int* __restrict__ lang_len,
                                             float* __restrict__ hbuf) {
    __shared__ __align__(16) float h_l[H_DIM];
    __shared__ float ghb[768];
    const int q = blockIdx.x, tid = threadIdx.x;
    int len = lang_len[q]; if (len > T_MAX) len = T_MAX;
    if (tid < H_DIM) h_l[tid] = 0.f;
    __syncthreads();
    const float4* w4 = (const float4*)(w_hh + tid * H_DIM);
    const float bh = b_hh[tid];
    for (int t = 0; t < len; ++t) {
        const float4* h4 = (const float4*)h_l;
        float a0 = 0.f, a1 = 0.f, a2 = 0.f, a3 = 0.f;
        #pragma unroll
        for (int i = 0; i < 64; i += 4) {
            a0 += dot4(w4[i],   h4[i]);
            a1 += dot4(w4[i+1], h4[i+1]);
            a2 += dot4(w4[i+2], h4[i+2]);
            a3 += dot4(w4[i+3], h4[i+3]);
        }
        ghb[tid] = bh + ((a0 + a1) + (a2 + a3));
        __syncthreads();
        if (tid < H_DIM) {
            const int base = (q * T_MAX + t) * 768;
            const float gir = gi[base + tid];
            const float giz = gi[base + 256 + tid];
            const float gin = gi[base + 512 + tid];
            const float r = sigmoidf_(gir + ghb[tid]);
            const float z = sigmoidf_(giz + ghb[256 + tid]);
            const float n = tanhf(gin + r * ghb[512 + tid]);
            h_l[tid] = (1.f - z) * n + z * h_l[tid];
        }
        __syncthreads();
    }
    if (tid < H_DIM) hbuf[q * H_DIM + tid] = h_l[tid];
}

// ---------------------------------------------------------------- lang head -> langc = lang_proj + fuse_b
__global__ __launch_bounds__(256) void k_lang(const float* __restrict__ hbuf,
                                              const float* __restrict__ w1, const float* __restrict__ b1,
                                              const float* __restrict__ w2, const float* __restrict__ b2,
                                              const float* __restrict__ fuse_w, const float* __restrict__ fuse_b,
                                              float* __restrict__ langc) {
    __shared__ float t1[Q_TOT][D_LANG];
    __shared__ float lg[Q_TOT][D_LANG];
    const int tid = threadIdx.x;
    for (int o = tid; o < Q_TOT * D_LANG; o += 256) {
        const int q = o >> 6, c = o & 63;
        const float4* h4 = (const float4*)(hbuf + q * H_DIM);
        const float4* w4 = (const float4*)(w1 + c * H_DIM);
        float acc = 0.f;
        #pragma unroll
        for (int i = 0; i < 64; ++i) acc += dot4(h4[i], w4[i]);
        t1[q][c] = fmaxf(acc + b1[c], 0.f);
    }
    __syncthreads();
    for (int o = tid; o < Q_TOT * D_LANG; o += 256) {
        const int q = o >> 6, c = o & 63;
        float acc = 0.f;
        #pragma unroll
        for (int k = 0; k < 64; ++k) acc += t1[q][k] * w2[c * 64 + k];
        lg[q][c] = acc + b2[c];
    }
    __syncthreads();
    for (int o = tid; o < Q_TOT * D_FUSE; o += 256) {
        const int q = o >> 7, d = o & 127;
        const float* wr = fuse_w + d * FW_LD + D_CAT;
        float acc = 0.f;
        #pragma unroll
        for (int k = 0; k < 64; ++k) acc += lg[q][k] * wr[k];
        langc[q * D_FUSE + d] = acc + fuse_b[d];
    }
}

// ---------------------------------------------------------------- fused sv_proj + relu-score + group partials
// grid NBLK3 (32 s-rows each), block 256: lanes = (dslice 0..3, q 0..31, sgroup 0..1)
__global__ __launch_bounds__(256) void k_fuse(const float* __restrict__ feat,
                                              const float* __restrict__ coords,
                                              const int* __restrict__ grps,
                                              const float* __restrict__ langc,
                                              const float* __restrict__ fuse_w,
                                              const float* __restrict__ heat_w,
                                              const float* __restrict__ heat_b,
                                              float* __restrict__ grp_part,
                                              int* __restrict__ cnt_part) {
    __shared__ __align__(16) float svin[SCHUNK][68];
    __shared__ __align__(16) float svp[SCHUNK][132];
    __shared__ float score[SCHUNK][Q_TOT];
    __shared__ int grps_l[SCHUNK];
    const int tid = threadIdx.x;
    const int s0 = blockIdx.x * SCHUNK;

    // thread-persistent registers for phase C
    const int dsl = tid & 3, q = (tid >> 2) & 31, sg = tid >> 7;
    float lc[32], wdr[32];
    #pragma unroll
    for (int i = 0; i < 32; ++i) {
        const int d = dsl * 32 + i;
        lc[i]  = langc[q * D_FUSE + d];
        wdr[i] = heat_w[D_FUSE + d] - heat_w[d];
    }
    const float hbd = heat_b[1] - heat_b[0];

    // stage sv inputs
    for (int i = tid; i < SCHUNK * D_SV; i += 256) {
        const int r = i >> 6, c = i & 63;
        svin[r][c] = feat[(s0 + r) * D_SV + c];
    }
    if (tid < SCHUNK * 3) { const int r = tid / 3, c = tid % 3; svin[r][D_SV + c] = coords[(s0 + r) * 3 + c]; }
    if (tid < SCHUNK) grps_l[tid] = grps[s0 + tid];
    __syncthreads();

    // sv_proj: 32x128 outputs, dot length 67
    for (int i = 0; i < 16; ++i) {
        const int o = tid + 256 * i;
        const int sl = o >> 7, d = o & 127;
        const float* wr = fuse_w + d * FW_LD;
        float a0 = 0.f, a1 = 0.f;
        #pragma unroll
        for (int k = 0; k < 66; k += 2) { a0 += svin[sl][k] * wr[k]; a1 += svin[sl][k+1] * wr[k+1]; }
        a0 += svin[sl][66] * wr[66];
        svp[sl][d] = a0 + a1;
    }
    __syncthreads();

    // scores: per (s, q): sigmoid( sum_d relu(svp+langc)*wd + hbd )
    for (int si = 0; si < 16; ++si) {
        const int sl = sg * 16 + si;
        const float4* sv4 = (const float4*)(&svp[sl][dsl * 32]);
        float part = 0.f;
        #pragma unroll
        for (int i4 = 0; i4 < 8; ++i4) {
            const float4 v = sv4[i4];
            part = fmaf(fmaxf(v.x + lc[i4*4+0], 0.f), wdr[i4*4+0], part);
            part = fmaf(fmaxf(v.y + lc[i4*4+1], 0.f), wdr[i4*4+1], part);
            part = fmaf(fmaxf(v.z + lc[i4*4+2], 0.f), wdr[i4*4+2], part);
            part = fmaf(fmaxf(v.w + lc[i4*4+3], 0.f), wdr[i4*4+3], part);
        }
        part += __shfl_xor(part, 1);
        part += __shfl_xor(part, 2);
        if (dsl == 0) score[sl][q] = sigmoidf_(part + hbd);
    }
    __syncthreads();

    // deterministic per-block group partials
    for (int i = 0; i < 8; ++i) {
        const int cell = tid + 256 * i;            // q*64+g
        const int qq = cell >> 6, g = cell & 63;
        float sum = 0.f;
        #pragma unroll
        for (int sl = 0; sl < SCHUNK; ++sl)
            sum += (grps_l[sl] == g) ? score[sl][qq] : 0.f;
        grp_part[blockIdx.x * (Q_TOT * G_TOT) + cell] = sum;
        if (cell < G_TOT) {
            int c = 0;
            #pragma unroll
            for (int sl = 0; sl < SCHUNK; ++sl) c += (grps_l[sl] == g);
            cnt_part[blockIdx.x * G_TOT + g] = c;
        }
    }
}

// ---------------------------------------------------------------- reduce partials + argmax per q
__global__ __launch_bounds__(256) void k_argmax(const float* __restrict__ grp_part,
                                                const int* __restrict__ cnt_part,
                                                int* __restrict__ best) {
    __shared__ float ps[4][G_TOT];
    __shared__ int   pc[4][G_TOT];
    __shared__ float sc[G_TOT];
    const int q = blockIdx.x, tid = threadIdx.x;
    const int bq = tid >> 6, g = tid & 63;
    float acc = 0.f; int cacc = 0;
    for (int b = bq; b < NBLK3; b += 4) {
        acc  += grp_part[b * (Q_TOT * G_TOT) + q * G_TOT + g];
        cacc += cnt_part[b * G_TOT + g];
    }
    ps[bq][g] = acc; pc[bq][g] = cacc;
    __syncthreads();
    if (tid < G_TOT) {
        const float s = ((ps[0][tid] + ps[1][tid]) + ps[2][tid]) + ps[3][tid];
        const int   c = ((pc[0][tid] + pc[1][tid]) + pc[2][tid]) + pc[3][tid];
        sc[tid] = s / (float)c;
    }
    __syncthreads();
    if (tid == 0) {
        float bv = sc[0]; int bi = 0;
        for (int g2 = 1; g2 < G_TOT; ++g2) if (sc[g2] > bv) { bv = sc[g2]; bi = g2; }
        best[q] = bi;
    }
}

// ---------------------------------------------------------------- smask[s] = bitmask over q of (grps[s]==best[q])
__global__ __launch_bounds__(256) void k_smask(const int* __restrict__ grps,
                                               const int* __restrict__ best,
                                               int* __restrict__ smask) {
    const int s = blockIdx.x * 256 + threadIdx.x;
    if (s >= S_TOT) return;
    const int g = grps[s];
    int m = 0;
    #pragma unroll
    for (int qq = 0; qq < Q_TOT; ++qq) m |= (best[qq] == g) ? (1 << qq) : 0;
    smask[s] = m;
}

// ---------------------------------------------------------------- obj_pts write + inter/union int reduction
__global__ __launch_bounds__(256) void k_out(const int* __restrict__ supervox,
                                             const int* __restrict__ gt,
                                             const int* __restrict__ smask,
                                             float* __restrict__ out,
                                             int* __restrict__ interG, int* __restrict__ unionG) {
    const int tid = threadIdx.x;
    const int gidx = blockIdx.x * 256 + tid;
    const int q = gidx & 31;
    const int nstride = (gridDim.x * 256) >> 5;
    int ai = 0, au = 0;
    for (int n = gidx >> 5; n < N_TOT; n += nstride) {
        const int m = smask[supervox[n]];
        const int o = (m >> q) & 1;
        const int g = gt[n * Q_TOT + q];
        out[n * Q_TOT + q] = (float)o;
        ai += o & g; au += o | g;
    }
    __shared__ int bi[Q_TOT], bu[Q_TOT];
    if (tid < Q_TOT) { bi[tid] = 0; bu[tid] = 0; }
    __syncthreads();
    atomicAdd(&bi[q], ai); atomicAdd(&bu[q], au);
    __syncthreads();
    if (tid < Q_TOT) { atomicAdd(&interG[tid], bi[tid]); atomicAdd(&unionG[tid], bu[tid]); }
}

// ---------------------------------------------------------------- ious
__global__ void k_iou(const int* __restrict__ interG, const int* __restrict__ unionG,
                      float* __restrict__ out) {
    const int q = threadIdx.x;
    if (q < Q_TOT)
        out[(size_t)N_TOT * Q_TOT + q] = (float)interG[q] / ((float)unionG[q] + 1e-5f);
}

extern "C" void kernel_launch(void* const* d_in, const int* in_sizes, int n_in,
                              void* d_out, int out_size, void* d_ws, size_t ws_size,
                              hipStream_t stream) {
    const float* lang_feat = (const float*)d_in[0];
    const float* feat      = (const float*)d_in[1];
    const float* coords    = (const float*)d_in[2];
    const int*   lang_len  = (const int*)d_in[3];
    const int*   grps      = (const int*)d_in[4];
    const int*   supervox  = (const int*)d_in[5];
    const int*   gt        = (const int*)d_in[6];
    const float* w_ih      = (const float*)d_in[7];
    const float* w_hh      = (const float*)d_in[8];
    const float* b_ih      = (const float*)d_in[9];
    const float* b_hh      = (const float*)d_in[10];
    const float* sqz_w1    = (const float*)d_in[11];
    const float* sqz_b1    = (const float*)d_in[12];
    const float* sqz_w2    = (const float*)d_in[13];
    const float* sqz_b2    = (const float*)d_in[14];
    const float* fuse_w    = (const float*)d_in[15];
    const float* fuse_b    = (const float*)d_in[16];
    const float* heat_w    = (const float*)d_in[17];
    const float* heat_b    = (const float*)d_in[18];
    float* out = (float*)d_out;

    float* gi       = (float*)d_ws;                       // 737280
    float* hbuf     = gi + 737280;                        // 8192
    float* langc    = hbuf + 8192;                        // 4096
    float* grp_part = langc + 4096;                       // 625*2048
    int*   cnt_part = (int*)(grp_part + NBLK3 * 2048);    // 625*64
    int*   best     = cnt_part + NBLK3 * 64;              // 32
    int*   smask    = best + 32;                          // 20000
    int*   interG   = smask + S_TOT;                      // 32
    int*   unionG   = interG + 32;                        // 32

    hipMemsetAsync(interG, 0, 64 * sizeof(int), stream);

    k_gi   <<<32 * 32, 768, 0, stream>>>(lang_feat, w_ih, b_ih, gi);
    k_gru  <<<32, 768, 0, stream>>>(gi, w_hh, b_hh, lang_len, hbuf);
    k_lang <<<1, 256, 0, stream>>>(hbuf, sqz_w1, sqz_b1, sqz_w2, sqz_b2, fuse_w, fuse_b, langc);
    k_fuse <<<NBLK3, 256, 0, stream>>>(feat, coords, grps, langc, fuse_w, heat_w, heat_b,
                                       grp_part, cnt_part);
    k_argmax<<<Q_TOT, 256, 0, stream>>>(grp_part, cnt_part, best);
    k_smask<<<(S_TOT + 255) / 256, 256, 0, stream>>>(grps, best, smask);
    k_out  <<<1024, 256, 0, stream>>>(supervox, gt, smask, out, interG, unionG);
    k_iou  <<<1, 64, 0, stream>>>(interG, unionG, out);
}

// Round 2
// 520.794 us; speedup vs baseline: 1.3719x; 1.3719x over previous
//
#include <hip/hip_runtime.h>
#include <hip/hip_bf16.h>
#include <math.h>

#define S_TOT 20000
#define Q_TOT 32
#define N_TOT 200000
#define T_MAX 30
#define G_TOT 64
#define D_IN 300
#define H_DIM 256
#define D_SV 64
#define D_LANG 64
#define D_FUSE 128
#define D_CAT 67          // D_SV + 3
#define FW_LD 131         // fuse_w leading dim (D_SV+3+D_LANG)
#define SCHUNK 32
#define NBLK3 (S_TOT / SCHUNK)   // 625
#define BPQ 8             // blocks per query in k_gru_coop
#define GRU_THR 384

__device__ __forceinline__ float dot4(float4 a, float4 b) {
    return a.x*b.x + a.y*b.y + a.z*b.z + a.w*b.w;
}
__device__ __forceinline__ float sigmoidf_(float x) { return 1.0f / (1.0f + expf(-x)); }

// ---------------------------------------------------------------- gi = x @ W_ih^T + b_ih
__global__ __launch_bounds__(768) void k_gi(const float* __restrict__ lang_feat,
                                            const float* __restrict__ w_ih,
                                            const float* __restrict__ b_ih,
                                            float* __restrict__ gi) {
    __shared__ __align__(16) float x_l[T_MAX * D_IN];   // 36 KB
    const int q = blockIdx.x >> 5, jsl = blockIdx.x & 31;
    const int tid = threadIdx.x;
    for (int i = tid; i < T_MAX * D_IN; i += 768)
        x_l[i] = lang_feat[q * (T_MAX * D_IN) + i];
    __syncthreads();
    const int t = tid / 24, jl = tid % 24;
    if (t < T_MAX) {
        const int j = jsl * 24 + jl;
        const float4* w4 = (const float4*)(w_ih + j * D_IN);
        const float4* x4 = (const float4*)(x_l + t * D_IN);
        float a0 = 0.f, a1 = 0.f, a2 = 0.f;
        #pragma unroll
        for (int i = 0; i < 75; i += 3) {
            a0 += dot4(w4[i],   x4[i]);
            a1 += dot4(w4[i+1], x4[i+1]);
            a2 += dot4(w4[i+2], x4[i+2]);
        }
        gi[(q * T_MAX + t) * 768 + j] = b_ih[j] + a0 + a1 + a2;
    }
}

// ---------------------------------------------------------------- cooperative GRU
// 256 blocks = 32 queries x 8 blocks. Block (q,b) owns h[j], j in [b*32, b*32+32).
// W_hh rows {j, 256+j, 512+j} live in VGPRs (64 f32/thread x 384 thr = 96 rows x 256).
// Per step: h (256 f32) staged from global (agent-scope) into 4-replica LDS,
// 96 dots of length 256 (4 lanes each), 32 lanes update h, one 8-block spin barrier.
__device__ __forceinline__ void qbar(int* c, int target) {
    __syncthreads();
    if (threadIdx.x == 0) {
        __threadfence();
        __hip_atomic_fetch_add(c, 1, __ATOMIC_RELEASE, __HIP_MEMORY_SCOPE_AGENT);
        while (__hip_atomic_load(c, __ATOMIC_ACQUIRE, __HIP_MEMORY_SCOPE_AGENT) < target)
            __builtin_amdgcn_s_sleep(2);
        __threadfence();
    }
    __syncthreads();
}

__global__ __launch_bounds__(GRU_THR) void k_gru_coop(const float* __restrict__ gi,
                                                      const float* __restrict__ w_hh,
                                                      const float* __restrict__ b_hh,
                                                      const int* __restrict__ lang_len,
                                                      float* __restrict__ h2,     // [2][32][256]
                                                      int* __restrict__ qcnt,     // [32][32] counters
                                                      float* __restrict__ hbuf) { // [32][256]
    __shared__ __align__(16) float hrep[4 * 260];   // 4 replicas of h, padded
    __shared__ float ghl[96];
    __shared__ float gil[T_MAX * 96];

    const int tid = threadIdx.x;
    const int q = blockIdx.x >> 3, b = blockIdx.x & 7;
    const int rr = tid >> 2, ql = tid & 3;          // rr in [0,96), ql in [0,4)
    const int gate = rr >> 5, jl = rr & 31;
    const int grow = gate * H_DIM + (b << 5) + jl;  // W_hh row index

    int len = lang_len[q]; if (len > T_MAX) len = T_MAX;

    // resident weights: 16 float4 = 64 floats per thread
    float4 wreg[16];
    {
        const float4* wsrc = (const float4*)(w_hh + (size_t)grow * H_DIM + ql * 64);
        #pragma unroll
        for (int i = 0; i < 16; ++i) wreg[i] = wsrc[i];
    }
    const float bh = b_hh[grow];

    // stage gi slices for this (q, b): gil[t*96 + gate*32 + jl]
    for (int i = tid; i < len * 96; i += GRU_THR) {
        const int t = i / 96, r = i % 96;
        gil[i] = gi[(q * T_MAX + t) * 768 + (r >> 5) * H_DIM + (b << 5) + (r & 31)];
    }

    int* cnt = qcnt + q * 32;
    float* hq0 = h2 + q * H_DIM;                    // buffer 0 for this query
    // h0 = 0 (each block zeroes its own slice)
    if (tid < 32)
        __hip_atomic_store(&hq0[(b << 5) + tid], 0.f, __ATOMIC_RELAXED, __HIP_MEMORY_SCOPE_AGENT);
    qbar(cnt, BPQ);                                  // epoch 1: h0 + gil ready

    const float4* hv = ((const float4*)hrep) + ql * 81;   // replica ql, k-offset ql*64

    for (int t = 0; t < len; ++t) {
        float* hsrc = h2 + (t & 1) * (Q_TOT * H_DIM) + q * H_DIM;
        float* hdst = h2 + ((t + 1) & 1) * (Q_TOT * H_DIM) + q * H_DIM;
        // stage h into 4 LDS replicas
        if (tid < H_DIM) {
            const float v = __hip_atomic_load(&hsrc[tid], __ATOMIC_RELAXED, __HIP_MEMORY_SCOPE_AGENT);
            hrep[tid] = v; hrep[260 + tid] = v; hrep[520 + tid] = v; hrep[780 + tid] = v;
        }
        __syncthreads();
        // 96 dots x 256, 4 lanes per dot
        float ax = 0.f, ay = 0.f, az = 0.f, aw = 0.f;
        #pragma unroll
        for (int i = 0; i < 16; ++i) {
            const float4 h4 = hv[i];
            ax = fmaf(wreg[i].x, h4.x, ax);
            ay = fmaf(wreg[i].y, h4.y, ay);
            az = fmaf(wreg[i].z, h4.z, az);
            aw = fmaf(wreg[i].w, h4.w, aw);
        }
        float s = (ax + ay) + (az + aw);
        s += __shfl_xor(s, 1);
        s += __shfl_xor(s, 2);
        if (ql == 0) ghl[rr] = s + bh;
        __syncthreads();
        // h update for this block's 32 indices
        if (tid < 32) {
            const float gr = gil[t * 96 + tid]      + ghl[tid];
            const float gz = gil[t * 96 + 32 + tid] + ghl[32 + tid];
            const float gn = gil[t * 96 + 64 + tid];
            const float hnd = ghl[64 + tid];
            const float r = sigmoidf_(gr);
            const float z = sigmoidf_(gz);
            const float n = tanhf(gn + r * hnd);
            const float hold = hrep[(b << 5) + tid];
            const float hnew = (1.f - z) * n + z * hold;
            __hip_atomic_store(&hdst[(b << 5) + tid], hnew, __ATOMIC_RELAXED, __HIP_MEMORY_SCOPE_AGENT);
            if (t == len - 1) hbuf[q * H_DIM + (b << 5) + tid] = hnew;
        }
        if (t < len - 1) qbar(cnt, BPQ * (t + 2));
    }
}

// ---------------------------------------------------------------- lang head -> langc = lang_proj + fuse_b
__global__ __launch_bounds__(256) void k_lang(const float* __restrict__ hbuf,
                                              const float* __restrict__ w1, const float* __restrict__ b1,
                                              const float* __restrict__ w2, const float* __restrict__ b2,
                                              const float* __restrict__ fuse_w, const float* __restrict__ fuse_b,
                                              float* __restrict__ langc) {
    __shared__ float t1[Q_TOT][D_LANG];
    __shared__ float lg[Q_TOT][D_LANG];
    const int tid = threadIdx.x;
    for (int o = tid; o < Q_TOT * D_LANG; o += 256) {
        const int q = o >> 6, c = o & 63;
        const float4* h4 = (const float4*)(hbuf + q * H_DIM);
        const float4* w4 = (const float4*)(w1 + c * H_DIM);
        float acc = 0.f;
        #pragma unroll
        for (int i = 0; i < 64; ++i) acc += dot4(h4[i], w4[i]);
        t1[q][c] = fmaxf(acc + b1[c], 0.f);
    }
    __syncthreads();
    for (int o = tid; o < Q_TOT * D_LANG; o += 256) {
        const int q = o >> 6, c = o & 63;
        float acc = 0.f;
        #pragma unroll
        for (int k = 0; k < 64; ++k) acc += t1[q][k] * w2[c * 64 + k];
        lg[q][c] = acc + b2[c];
    }
    __syncthreads();
    for (int o = tid; o < Q_TOT * D_FUSE; o += 256) {
        const int q = o >> 7, d = o & 127;
        const float* wr = fuse_w + d * FW_LD + D_CAT;
        float acc = 0.f;
        #pragma unroll
        for (int k = 0; k < 64; ++k) acc += lg[q][k] * wr[k];
        langc[q * D_FUSE + d] = acc + fuse_b[d];
    }
}

// ---------------------------------------------------------------- fused sv_proj + relu-score + group partials
__global__ __launch_bounds__(256) void k_fuse(const float* __restrict__ feat,
                                              const float* __restrict__ coords,
                                              const int* __restrict__ grps,
                                              const float* __restrict__ langc,
                                              const float* __restrict__ fuse_w,
                                              const float* __restrict__ heat_w,
                                              const float* __restrict__ heat_b,
                                              float* __restrict__ grp_part,
                                              int* __restrict__ cnt_part) {
    __shared__ __align__(16) float svin[SCHUNK][68];
    __shared__ __align__(16) float svp[SCHUNK][132];
    __shared__ float score[SCHUNK][Q_TOT];
    __shared__ int grps_l[SCHUNK];
    const int tid = threadIdx.x;
    const int s0 = blockIdx.x * SCHUNK;

    const int dsl = tid & 3, q = (tid >> 2) & 31, sg = tid >> 7;
    float lc[32], wdr[32];
    #pragma unroll
    for (int i = 0; i < 32; ++i) {
        const int d = dsl * 32 + i;
        lc[i]  = langc[q * D_FUSE + d];
        wdr[i] = heat_w[D_FUSE + d] - heat_w[d];
    }
    const float hbd = heat_b[1] - heat_b[0];

    for (int i = tid; i < SCHUNK * D_SV; i += 256) {
        const int r = i >> 6, c = i & 63;
        svin[r][c] = feat[(s0 + r) * D_SV + c];
    }
    if (tid < SCHUNK * 3) { const int r = tid / 3, c = tid % 3; svin[r][D_SV + c] = coords[(s0 + r) * 3 + c]; }
    if (tid < SCHUNK) grps_l[tid] = grps[s0 + tid];
    __syncthreads();

    for (int i = 0; i < 16; ++i) {
        const int o = tid + 256 * i;
        const int sl = o >> 7, d = o & 127;
        const float* wr = fuse_w + d * FW_LD;
        float a0 = 0.f, a1 = 0.f;
        #pragma unroll
        for (int k = 0; k < 66; k += 2) { a0 += svin[sl][k] * wr[k]; a1 += svin[sl][k+1] * wr[k+1]; }
        a0 += svin[sl][66] * wr[66];
        svp[sl][d] = a0 + a1;
    }
    __syncthreads();

    for (int si = 0; si < 16; ++si) {
        const int sl = sg * 16 + si;
        const float4* sv4 = (const float4*)(&svp[sl][dsl * 32]);
        float part = 0.f;
        #pragma unroll
        for (int i4 = 0; i4 < 8; ++i4) {
            const float4 v = sv4[i4];
            part = fmaf(fmaxf(v.x + lc[i4*4+0], 0.f), wdr[i4*4+0], part);
            part = fmaf(fmaxf(v.y + lc[i4*4+1], 0.f), wdr[i4*4+1], part);
            part = fmaf(fmaxf(v.z + lc[i4*4+2], 0.f), wdr[i4*4+2], part);
            part = fmaf(fmaxf(v.w + lc[i4*4+3], 0.f), wdr[i4*4+3], part);
        }
        part += __shfl_xor(part, 1);
        part += __shfl_xor(part, 2);
        if (dsl == 0) score[sl][q] = sigmoidf_(part + hbd);
    }
    __syncthreads();

    for (int i = 0; i < 8; ++i) {
        const int cell = tid + 256 * i;            // q*64+g
        const int qq = cell >> 6, g = cell & 63;
        float sum = 0.f;
        #pragma unroll
        for (int sl = 0; sl < SCHUNK; ++sl)
            sum += (grps_l[sl] == g) ? score[sl][qq] : 0.f;
        grp_part[blockIdx.x * (Q_TOT * G_TOT) + cell] = sum;
        if (cell < G_TOT) {
            int c = 0;
            #pragma unroll
            for (int sl = 0; sl < SCHUNK; ++sl) c += (grps_l[sl] == g);
            cnt_part[blockIdx.x * G_TOT + g] = c;
        }
    }
}

// ---------------------------------------------------------------- reduce partials + argmax per q
__global__ __launch_bounds__(256) void k_argmax(const float* __restrict__ grp_part,
                                                const int* __restrict__ cnt_part,
                                                int* __restrict__ best) {
    __shared__ float ps[4][G_TOT];
    __shared__ int   pc[4][G_TOT];
    __shared__ float sc[G_TOT];
    const int q = blockIdx.x, tid = threadIdx.x;
    const int bq = tid >> 6, g = tid & 63;
    float acc = 0.f; int cacc = 0;
    for (int b = bq; b < NBLK3; b += 4) {
        acc  += grp_part[b * (Q_TOT * G_TOT) + q * G_TOT + g];
        cacc += cnt_part[b * G_TOT + g];
    }
    ps[bq][g] = acc; pc[bq][g] = cacc;
    __syncthreads();
    if (tid < G_TOT) {
        const float s = ((ps[0][tid] + ps[1][tid]) + ps[2][tid]) + ps[3][tid];
        const int   c = ((pc[0][tid] + pc[1][tid]) + pc[2][tid]) + pc[3][tid];
        sc[tid] = s / (float)c;
    }
    __syncthreads();
    if (tid == 0) {
        float bv = sc[0]; int bi = 0;
        for (int g2 = 1; g2 < G_TOT; ++g2) if (sc[g2] > bv) { bv = sc[g2]; bi = g2; }
        best[q] = bi;
    }
}

// ---------------------------------------------------------------- smask[s] = bitmask over q
__global__ __launch_bounds__(256) void k_smask(const int* __restrict__ grps,
                                               const int* __restrict__ best,
                                               int* __restrict__ smask) {
    const int s = blockIdx.x * 256 + threadIdx.x;
    if (s >= S_TOT) return;
    const int g = grps[s];
    int m = 0;
    #pragma unroll
    for (int qq = 0; qq < Q_TOT; ++qq) m |= (best[qq] == g) ? (1 << qq) : 0;
    smask[s] = m;
}

// ---------------------------------------------------------------- obj_pts write + inter/union reduction
__global__ __launch_bounds__(256) void k_out(const int* __restrict__ supervox,
                                             const int* __restrict__ gt,
                                             const int* __restrict__ smask,
                                             float* __restrict__ out,
                                             int* __restrict__ interG, int* __restrict__ unionG) {
    const int tid = threadIdx.x;
    const int gidx = blockIdx.x * 256 + tid;
    const int q = gidx & 31;
    const int nstride = (gridDim.x * 256) >> 5;
    int ai = 0, au = 0;
    for (int n = gidx >> 5; n < N_TOT; n += nstride) {
        const int m = smask[supervox[n]];
        const int o = (m >> q) & 1;
        const int g = gt[n * Q_TOT + q];
        out[n * Q_TOT + q] = (float)o;
        ai += o & g; au += o | g;
    }
    __shared__ int bi[Q_TOT], bu[Q_TOT];
    if (tid < Q_TOT) { bi[tid] = 0; bu[tid] = 0; }
    __syncthreads();
    atomicAdd(&bi[q], ai); atomicAdd(&bu[q], au);
    __syncthreads();
    if (tid < Q_TOT) { atomicAdd(&interG[tid], bi[tid]); atomicAdd(&unionG[tid], bu[tid]); }
}

// ---------------------------------------------------------------- ious
__global__ void k_iou(const int* __restrict__ interG, const int* __restrict__ unionG,
                      float* __restrict__ out) {
    const int q = threadIdx.x;
    if (q < Q_TOT)
        out[(size_t)N_TOT * Q_TOT + q] = (float)interG[q] / ((float)unionG[q] + 1e-5f);
}

extern "C" void kernel_launch(void* const* d_in, const int* in_sizes, int n_in,
                              void* d_out, int out_size, void* d_ws, size_t ws_size,
                              hipStream_t stream) {
    const float* lang_feat = (const float*)d_in[0];
    const float* feat      = (const float*)d_in[1];
    const float* coords    = (const float*)d_in[2];
    const int*   lang_len  = (const int*)d_in[3];
    const int*   grps      = (const int*)d_in[4];
    const int*   supervox  = (const int*)d_in[5];
    const int*   gt        = (const int*)d_in[6];
    const float* w_ih      = (const float*)d_in[7];
    const float* w_hh      = (const float*)d_in[8];
    const float* b_ih      = (const float*)d_in[9];
    const float* b_hh      = (const float*)d_in[10];
    const float* sqz_w1    = (const float*)d_in[11];
    const float* sqz_b1    = (const float*)d_in[12];
    const float* sqz_w2    = (const float*)d_in[13];
    const float* sqz_b2    = (const float*)d_in[14];
    const float* fuse_w    = (const float*)d_in[15];
    const float* fuse_b    = (const float*)d_in[16];
    const float* heat_w    = (const float*)d_in[17];
    const float* heat_b    = (const float*)d_in[18];
    float* out = (float*)d_out;

    float* gi       = (float*)d_ws;                       // 737280
    float* hbuf     = gi + 737280;                        // 8192
    float* langc    = hbuf + 8192;                        // 4096
    float* grp_part = langc + 4096;                       // 625*2048
    int*   cnt_part = (int*)(grp_part + NBLK3 * 2048);    // 625*64
    int*   best     = cnt_part + NBLK3 * 64;              // 32
    int*   smask    = best + 32;                          // 20000
    int*   interG   = smask + S_TOT;                      // 32
    int*   unionG   = interG + 32;                        // 32
    float* h2       = (float*)(unionG + 32);              // 2*32*256
    int*   qcnt     = (int*)(h2 + 2 * Q_TOT * H_DIM);     // 32*32

    hipMemsetAsync(interG, 0, 64 * sizeof(int), stream);
    hipMemsetAsync(qcnt, 0, Q_TOT * 32 * sizeof(int), stream);

    k_gi      <<<32 * 32, 768, 0, stream>>>(lang_feat, w_ih, b_ih, gi);
    k_gru_coop<<<Q_TOT * BPQ, GRU_THR, 0, stream>>>(gi, w_hh, b_hh, lang_len, h2, qcnt, hbuf);
    k_lang    <<<1, 256, 0, stream>>>(hbuf, sqz_w1, sqz_b1, sqz_w2, sqz_b2, fuse_w, fuse_b, langc);
    k_fuse    <<<NBLK3, 256, 0, stream>>>(feat, coords, grps, langc, fuse_w, heat_w, heat_b,
                                          grp_part, cnt_part);
    k_argmax  <<<Q_TOT, 256, 0, stream>>>(grp_part, cnt_part, best);
    k_smask   <<<(S_TOT + 255) / 256, 256, 0, stream>>>(grps, best, smask);
    k_out     <<<1024, 256, 0, stream>>>(supervox, gt, smask, out, interG, unionG);
    k_iou     <<<1, 64, 0, stream>>>(interG, unionG, out);
}

// Round 4
// 321.559 us; speedup vs baseline: 2.2220x; 1.6196x over previous
//
#include <hip/hip_runtime.h>
#include <hip/hip_bf16.h>
#include <math.h>

#define S_TOT 20000
#define Q_TOT 32
#define N_TOT 200000
#define T_MAX 30
#define G_TOT 64
#define D_IN 300
#define H_DIM 256
#define D_SV 64
#define D_LANG 64
#define D_FUSE 128
#define D_CAT 67
#define FW_LD 131
#define SCHUNK 32
#define NBLK3 (S_TOT / SCHUNK)   // 625
#define BPQ 4
#define GT 384
#define XPAD 308                 // x_l row stride in k_gi (16B aligned)

__device__ __forceinline__ float dot4(float4 a, float4 b) {
    return a.x*b.x + a.y*b.y + a.z*b.z + a.w*b.w;
}
__device__ __forceinline__ float sigmoidf_(float x) { return 1.0f / (1.0f + expf(-x)); }
__device__ __forceinline__ unsigned long long pack2(float a, float b) {
    return ((unsigned long long)__float_as_uint(b) << 32) | (unsigned long long)__float_as_uint(a);
}

// ---------------------------------------------------------------- k_gi: gi = x @ W_ih^T + b_ih
// blocks 0..1023: (q, jsl); block 1024: weight transposes; block 1025: zero counters.
__global__ __launch_bounds__(768) void k_gi(const float* __restrict__ lang_feat,
                                            const float* __restrict__ w_ih,
                                            const float* __restrict__ b_ih,
                                            const float* __restrict__ fuse_w,
                                            const float* __restrict__ sqz_w1,
                                            const float* __restrict__ sqz_w2,
                                            const float* __restrict__ heat_w,
                                            float* __restrict__ gi,
                                            float* __restrict__ fwt,
                                            float* __restrict__ w1t,
                                            float* __restrict__ w2t,
                                            float* __restrict__ wdr,
                                            int* __restrict__ qcnt,
                                            int* __restrict__ interG,
                                            int* __restrict__ unionG,
                                            int* __restrict__ ticket) {
    const int tid = threadIdx.x;
    if (blockIdx.x >= 1024) {
        if (blockIdx.x == 1024) {
            for (int i = tid; i < FW_LD * D_FUSE; i += 768)
                fwt[(i % FW_LD) * D_FUSE + (i / FW_LD)] = fuse_w[i];
            for (int i = tid; i < D_LANG * H_DIM; i += 768)
                w1t[(i & 255) * D_LANG + (i >> 8)] = sqz_w1[i];
            for (int i = tid; i < D_LANG * D_LANG; i += 768)
                w2t[(i & 63) * D_LANG + (i >> 6)] = sqz_w2[i];
            if (tid < D_FUSE) wdr[tid] = heat_w[D_FUSE + tid] - heat_w[tid];
        } else {
            for (int i = tid; i < Q_TOT * 32; i += 768) qcnt[i] = 0;
            if (tid < Q_TOT) { interG[tid] = 0; unionG[tid] = 0; }
            if (tid == 0) *ticket = 0;
        }
        return;
    }
    __shared__ __align__(16) float x_l[T_MAX * XPAD];
    const int q = blockIdx.x >> 5, jsl = blockIdx.x & 31;
    for (int i = tid; i < T_MAX * D_IN; i += 768)
        x_l[(i / D_IN) * XPAD + (i % D_IN)] = lang_feat[q * (T_MAX * D_IN) + i];
    __syncthreads();
    const int jloc = tid >> 5, t = tid & 31;
    if (t < T_MAX) {
        const int j = jsl * 24 + jloc;
        const float4* w4 = (const float4*)(w_ih + j * D_IN);
        const float4* x4 = (const float4*)(x_l + t * XPAD);
        float a0 = 0.f, a1 = 0.f, a2 = 0.f;
        #pragma unroll
        for (int i = 0; i < 75; i += 3) {
            a0 += dot4(w4[i],   x4[i]);
            a1 += dot4(w4[i+1], x4[i+1]);
            a2 += dot4(w4[i+2], x4[i+2]);
        }
        gi[(q * T_MAX + t) * 768 + j] = b_ih[j] + a0 + a1 + a2;
    }
}

// ---------------------------------------------------------------- cooperative GRU, 4 blocks/query
// Block (q,b): rows {gate*256 + b*64 + jl}; thread t: rl=t>>1 (row), hf=t&1 (k-half).
// Weights resident: 32 float4/thread (launch_bounds min-waves=1 lifts the VGPR cap).
// No threadfence: h via u64 relaxed-AGENT atomics, ordered by s_waitcnt vmcnt(0)
// before a relaxed flag increment.
__global__ __launch_bounds__(GT, 1) void k_gru4(const float* __restrict__ gi,
                                                const float* __restrict__ w_hh,
                                                const float* __restrict__ b_hh,
                                                const int* __restrict__ lang_len,
                                                float* __restrict__ hg,      // [2][32][256]
                                                int* __restrict__ qcnt,      // [32][32]
                                                float* __restrict__ hbuf) {  // [32][256]
    __shared__ __align__(16) float hl[H_DIM];
    __shared__ float ghl[192];
    __shared__ float hown[64];
    __shared__ float gil[T_MAX * 192];

    const int tid = threadIdx.x;
    const int q = blockIdx.x >> 2, b = blockIdx.x & 3;
    const int rl = tid >> 1, hf = tid & 1;
    const int gate = rl >> 6, jl = rl & 63;
    const int grow = gate * H_DIM + (b << 6) + jl;
    int len = lang_len[q]; if (len > T_MAX) len = T_MAX; if (len < 1) len = 1;

    // resident weights: 32 float4 = 128 floats (half-row of one gate row)
    float4 w[32];
    {
        const float4* wsrc = (const float4*)(w_hh + (size_t)grow * H_DIM + hf * 128);
        #pragma unroll
        for (int i = 0; i < 32; ++i) w[i] = wsrc[i];
    }
    const float bh = b_hh[grow];

    // stage gi slices: gil[t*192 + gate*64 + jl]
    for (int i = tid; i < len * 192; i += GT) {
        const int t = i / 192, r = i % 192;
        gil[i] = gi[(q * T_MAX + t) * 768 + (r >> 6) * H_DIM + (b << 6) + (r & 63)];
    }
    __syncthreads();

    // step 0: h0 = 0  =>  gh = b_hh
    if (tid < 64) {
        const float bhr = b_hh[(b << 6) + tid];
        const float bhz = b_hh[H_DIM + (b << 6) + tid];
        const float bhn = b_hh[2 * H_DIM + (b << 6) + tid];
        const float r = sigmoidf_(gil[tid] + bhr);
        const float z = sigmoidf_(gil[64 + tid] + bhz);
        const float n = tanhf(gil[128 + tid] + r * bhn);
        hown[tid] = (1.f - z) * n;
    }
    __syncthreads();
    {
        unsigned long long* dst = (unsigned long long*)(hg + Q_TOT * H_DIM + q * H_DIM);
        if (tid < 32)
            __hip_atomic_store(dst + ((b << 5) + tid),
                               pack2(hown[2 * tid], hown[2 * tid + 1]),
                               __ATOMIC_RELAXED, __HIP_MEMORY_SCOPE_AGENT);
    }
    asm volatile("s_waitcnt vmcnt(0)" ::: "memory");
    if (tid == 0)
        __hip_atomic_fetch_add(qcnt + q * 32, 1, __ATOMIC_RELAXED, __HIP_MEMORY_SCOPE_AGENT);

    for (int t = 1; t < len; ++t) {
        if (tid == 0) {
            while (__hip_atomic_load(qcnt + q * 32, __ATOMIC_RELAXED, __HIP_MEMORY_SCOPE_AGENT) < BPQ * t)
                __builtin_amdgcn_s_sleep(1);
        }
        __syncthreads();
        const unsigned long long* hsrc =
            (const unsigned long long*)(hg + (t & 1) * (Q_TOT * H_DIM) + q * H_DIM);
        if (tid < 128) {
            const unsigned long long v =
                __hip_atomic_load(hsrc + tid, __ATOMIC_RELAXED, __HIP_MEMORY_SCOPE_AGENT);
            hl[2 * tid]     = __uint_as_float((unsigned)(v & 0xffffffffu));
            hl[2 * tid + 1] = __uint_as_float((unsigned)(v >> 32));
        }
        __syncthreads();
        const float4* h4 = (const float4*)(hl + hf * 128);
        float ax = 0.f, ay = 0.f, az = 0.f, aw = 0.f;
        #pragma unroll
        for (int i = 0; i < 32; ++i) {
            const float4 hv = h4[i];
            ax = fmaf(w[i].x, hv.x, ax);
            ay = fmaf(w[i].y, hv.y, ay);
            az = fmaf(w[i].z, hv.z, az);
            aw = fmaf(w[i].w, hv.w, aw);
        }
        float s = (ax + ay) + (az + aw);
        s += __shfl_xor(s, 1);
        ghl[rl] = s + bh;                      // both half-lanes write the same value
        __syncthreads();
        if (tid < 64) {
            const float* gt_ = gil + t * 192;
            const float r = sigmoidf_(gt_[tid] + ghl[tid]);
            const float z = sigmoidf_(gt_[64 + tid] + ghl[64 + tid]);
            const float n = tanhf(gt_[128 + tid] + r * ghl[128 + tid]);
            const float hold = hl[(b << 6) + tid];
            hown[tid] = (1.f - z) * n + z * hold;
        }
        __syncthreads();
        if (t == len - 1) break;
        {
            unsigned long long* dst =
                (unsigned long long*)(hg + ((t + 1) & 1) * (Q_TOT * H_DIM) + q * H_DIM);
            if (tid < 32)
                __hip_atomic_store(dst + ((b << 5) + tid),
                                   pack2(hown[2 * tid], hown[2 * tid + 1]),
                                   __ATOMIC_RELAXED, __HIP_MEMORY_SCOPE_AGENT);
        }
        asm volatile("s_waitcnt vmcnt(0)" ::: "memory");
        if (tid == 0)
            __hip_atomic_fetch_add(qcnt + q * 32, 1, __ATOMIC_RELAXED, __HIP_MEMORY_SCOPE_AGENT);
    }
    if (tid < 64) hbuf[q * H_DIM + (b << 6) + tid] = hown[tid];
}

// ---------------------------------------------------------------- lang head (transposed weights)
__global__ __launch_bounds__(256) void k_lang(const float* __restrict__ hbuf,
                                              const float* __restrict__ w1t, const float* __restrict__ b1,
                                              const float* __restrict__ w2t, const float* __restrict__ b2,
                                              const float* __restrict__ fwt, const float* __restrict__ fuse_b,
                                              float* __restrict__ langc) {
    __shared__ float t1[Q_TOT * D_LANG];
    __shared__ float lg[Q_TOT * D_LANG];
    const int tid = threadIdx.x;
    {   // t1 = relu(h @ w1^T + b1): thread owns c = tid&63, queries q0 + 4i
        const int c = tid & 63, q0 = tid >> 6;
        float acc[8] = {0.f,0.f,0.f,0.f,0.f,0.f,0.f,0.f};
        for (int k = 0; k < H_DIM; ++k) {
            const float wv = w1t[k * D_LANG + c];
            #pragma unroll
            for (int i = 0; i < 8; ++i)
                acc[i] = fmaf(hbuf[(q0 + 4 * i) * H_DIM + k], wv, acc[i]);
        }
        const float bb = b1[c];
        #pragma unroll
        for (int i = 0; i < 8; ++i) t1[(q0 + 4 * i) * D_LANG + c] = fmaxf(acc[i] + bb, 0.f);
    }
    __syncthreads();
    {   // lg = t1 @ w2^T + b2
        const int c = tid & 63, q0 = tid >> 6;
        float acc[8] = {0.f,0.f,0.f,0.f,0.f,0.f,0.f,0.f};
        for (int k = 0; k < D_LANG; ++k) {
            const float wv = w2t[k * D_LANG + c];
            #pragma unroll
            for (int i = 0; i < 8; ++i)
                acc[i] = fmaf(t1[(q0 + 4 * i) * D_LANG + k], wv, acc[i]);
        }
        const float bb = b2[c];
        #pragma unroll
        for (int i = 0; i < 8; ++i) lg[(q0 + 4 * i) * D_LANG + c] = acc[i] + bb;
    }
    __syncthreads();
    {   // langc = lg @ fuse_w[:,67:]^T + fuse_b
        const int d = tid & 127, qg = tid >> 7;
        float acc[16];
        #pragma unroll
        for (int i = 0; i < 16; ++i) acc[i] = 0.f;
        for (int k = 0; k < D_LANG; ++k) {
            const float wv = fwt[(D_CAT + k) * D_FUSE + d];
            #pragma unroll
            for (int i = 0; i < 16; ++i)
                acc[i] = fmaf(lg[(qg + 2 * i) * D_LANG + k], wv, acc[i]);
        }
        const float bb = fuse_b[d];
        #pragma unroll
        for (int i = 0; i < 16; ++i) langc[(qg + 2 * i) * D_FUSE + d] = acc[i] + bb;
    }
}

// ---------------------------------------------------------------- fused sv_proj + score + group partials
__global__ __launch_bounds__(256) void k_fuse(const float* __restrict__ feat,
                                              const float* __restrict__ coords,
                                              const int* __restrict__ grps,
                                              const float* __restrict__ langc,
                                              const float* __restrict__ fwt,
                                              const float* __restrict__ wdr_g,
                                              const float* __restrict__ heat_b,
                                              float* __restrict__ grp_part,
                                              int* __restrict__ cnt_part) {
    __shared__ __align__(16) float svin[SCHUNK][68];
    __shared__ __align__(16) float svp[SCHUNK][132];
    __shared__ float score[SCHUNK][Q_TOT];
    __shared__ int grps_l[SCHUNK];
    const int tid = threadIdx.x;
    const int s0 = blockIdx.x * SCHUNK;

    const int dsl = tid & 3, q = (tid >> 2) & 31, sg = tid >> 7;
    float lc[32], wdr[32];
    #pragma unroll
    for (int i = 0; i < 32; ++i) {
        const int d = dsl * 32 + i;
        lc[i]  = langc[q * D_FUSE + d];
        wdr[i] = wdr_g[d];
    }
    const float hbd = heat_b[1] - heat_b[0];

    for (int i = tid; i < SCHUNK * D_SV; i += 256) {
        const int r = i >> 6, c = i & 63;
        svin[r][c] = feat[(s0 + r) * D_SV + c];
    }
    if (tid < SCHUNK * 3) { const int r = tid / 3, c = tid % 3; svin[r][D_SV + c] = coords[(s0 + r) * 3 + c]; }
    if (tid < SCHUNK) grps_l[tid] = grps[s0 + tid];
    __syncthreads();

    {   // sv_proj with coalesced fwt reads; thread owns column d, 16 s-rows
        const int d = tid & 127, sl0 = tid >> 7;
        float acc[16];
        #pragma unroll
        for (int i = 0; i < 16; ++i) acc[i] = 0.f;
        for (int k = 0; k < D_CAT; ++k) {
            const float wv = fwt[k * D_FUSE + d];
            #pragma unroll
            for (int i = 0; i < 16; ++i)
                acc[i] = fmaf(svin[sl0 + 2 * i][k], wv, acc[i]);
        }
        #pragma unroll
        for (int i = 0; i < 16; ++i) svp[sl0 + 2 * i][d] = acc[i];
    }
    __syncthreads();

    for (int si = 0; si < 16; ++si) {
        const int sl = sg * 16 + si;
        const float4* sv4 = (const float4*)(&svp[sl][dsl * 32]);
        float part = 0.f;
        #pragma unroll
        for (int i4 = 0; i4 < 8; ++i4) {
            const float4 v = sv4[i4];
            part = fmaf(fmaxf(v.x + lc[i4*4+0], 0.f), wdr[i4*4+0], part);
            part = fmaf(fmaxf(v.y + lc[i4*4+1], 0.f), wdr[i4*4+1], part);
            part = fmaf(fmaxf(v.z + lc[i4*4+2], 0.f), wdr[i4*4+2], part);
            part = fmaf(fmaxf(v.w + lc[i4*4+3], 0.f), wdr[i4*4+3], part);
        }
        part += __shfl_xor(part, 1);
        part += __shfl_xor(part, 2);
        if (dsl == 0) score[sl][q] = sigmoidf_(part + hbd);
    }
    __syncthreads();

    for (int i = 0; i < 8; ++i) {
        const int cell = tid + 256 * i;            // q*64+g
        const int qq = cell >> 6, g = cell & 63;
        float sum = 0.f;
        #pragma unroll
        for (int sl = 0; sl < SCHUNK; ++sl)
            sum += (grps_l[sl] == g) ? score[sl][qq] : 0.f;
        grp_part[blockIdx.x * (Q_TOT * G_TOT) + cell] = sum;
        if (cell < G_TOT) {
            int c = 0;
            #pragma unroll
            for (int sl = 0; sl < SCHUNK; ++sl) c += (grps_l[sl] == g);
            cnt_part[blockIdx.x * G_TOT + g] = c;
        }
    }
}

// ---------------------------------------------------------------- reduce partials + argmax per q
__global__ __launch_bounds__(256) void k_argmax(const float* __restrict__ grp_part,
                                                const int* __restrict__ cnt_part,
                                                int* __restrict__ best) {
    __shared__ float ps[4][G_TOT];
    __shared__ int   pc[4][G_TOT];
    __shared__ float sc[G_TOT];
    const int q = blockIdx.x, tid = threadIdx.x;
    const int bq = tid >> 6, g = tid & 63;
    float acc = 0.f; int cacc = 0;
    for (int b = bq; b < NBLK3; b += 4) {
        acc  += grp_part[b * (Q_TOT * G_TOT) + q * G_TOT + g];
        cacc += cnt_part[b * G_TOT + g];
    }
    ps[bq][g] = acc; pc[bq][g] = cacc;
    __syncthreads();
    if (tid < G_TOT) {
        const float s = ((ps[0][tid] + ps[1][tid]) + ps[2][tid]) + ps[3][tid];
        const int   c = ((pc[0][tid] + pc[1][tid]) + pc[2][tid]) + pc[3][tid];
        sc[tid] = s / (float)c;
    }
    __syncthreads();
    if (tid == 0) {
        float bv = sc[0]; int bi = 0;
        for (int g2 = 1; g2 < G_TOT; ++g2) if (sc[g2] > bv) { bv = sc[g2]; bi = g2; }
        best[q] = bi;
    }
}

// ---------------------------------------------------------------- smask[s] = bitmask over q
__global__ __launch_bounds__(256) void k_smask(const int* __restrict__ grps,
                                               const int* __restrict__ best,
                                               int* __restrict__ smask) {
    const int s = blockIdx.x * 256 + threadIdx.x;
    if (s >= S_TOT) return;
    const int g = grps[s];
    int m = 0;
    #pragma unroll
    for (int qq = 0; qq < Q_TOT; ++qq) m |= (best[qq] == g) ? (1 << qq) : 0;
    smask[s] = m;
}

// ---------------------------------------------------------------- obj_pts + inter/union + iou (ticketed)
__global__ __launch_bounds__(256) void k_out(const int* __restrict__ supervox,
                                             const int* __restrict__ gt,
                                             const int* __restrict__ smask,
                                             float* __restrict__ out,
                                             int* __restrict__ interG, int* __restrict__ unionG,
                                             int* __restrict__ ticket) {
    const int tid = threadIdx.x;
    const int gidx = blockIdx.x * 256 + tid;
    const int q = gidx & 31;
    const int nstride = (gridDim.x * 256) >> 5;
    int ai = 0, au = 0;
    for (int n = gidx >> 5; n < N_TOT; n += nstride) {
        const int m = smask[supervox[n]];
        const int o = (m >> q) & 1;
        const int g = gt[n * Q_TOT + q];
        out[n * Q_TOT + q] = (float)o;
        ai += o & g; au += o | g;
    }
    __shared__ int bi[Q_TOT], bu[Q_TOT];
    __shared__ int islast;
    if (tid < Q_TOT) { bi[tid] = 0; bu[tid] = 0; }
    __syncthreads();
    atomicAdd(&bi[q], ai); atomicAdd(&bu[q], au);
    __syncthreads();
    if (tid < Q_TOT) { atomicAdd(&interG[tid], bi[tid]); atomicAdd(&unionG[tid], bu[tid]); }
    asm volatile("s_waitcnt vmcnt(0)" ::: "memory");
    if (tid == 0) {
        const int old = __hip_atomic_fetch_add(ticket, 1, __ATOMIC_RELAXED, __HIP_MEMORY_SCOPE_AGENT);
        islast = (old == (int)gridDim.x - 1) ? 1 : 0;
    }
    __syncthreads();
    if (islast && tid < Q_TOT) {
        const int iv = __hip_atomic_load(&interG[tid], __ATOMIC_RELAXED, __HIP_MEMORY_SCOPE_AGENT);
        const int uv = __hip_atomic_load(&unionG[tid], __ATOMIC_RELAXED, __HIP_MEMORY_SCOPE_AGENT);
        out[(size_t)N_TOT * Q_TOT + tid] = (float)iv / ((float)uv + 1e-5f);
    }
}

extern "C" void kernel_launch(void* const* d_in, const int* in_sizes, int n_in,
                              void* d_out, int out_size, void* d_ws, size_t ws_size,
                              hipStream_t stream) {
    const float* lang_feat = (const float*)d_in[0];
    const float* feat      = (const float*)d_in[1];
    const float* coords    = (const float*)d_in[2];
    const int*   lang_len  = (const int*)d_in[3];
    const int*   grps      = (const int*)d_in[4];
    const int*   supervox  = (const int*)d_in[5];
    const int*   gt        = (const int*)d_in[6];
    const float* w_ih      = (const float*)d_in[7];
    const float* w_hh      = (const float*)d_in[8];
    const float* b_ih      = (const float*)d_in[9];
    const float* b_hh      = (const float*)d_in[10];
    const float* sqz_w1    = (const float*)d_in[11];
    const float* sqz_b1    = (const float*)d_in[12];
    const float* sqz_w2    = (const float*)d_in[13];
    const float* sqz_b2    = (const float*)d_in[14];
    const float* fuse_w    = (const float*)d_in[15];
    const float* fuse_b    = (const float*)d_in[16];
    const float* heat_w    = (const float*)d_in[17];
    const float* heat_b    = (const float*)d_in[18];
    float* out = (float*)d_out;

    float* gi       = (float*)d_ws;                       // 737280
    float* hbuf     = gi + 737280;                        // 8192
    float* langc    = hbuf + 8192;                        // 4096
    float* grp_part = langc + 4096;                       // 625*2048
    int*   cnt_part = (int*)(grp_part + NBLK3 * 2048);    // 625*64
    int*   best     = cnt_part + NBLK3 * 64;              // 32
    int*   smask    = best + 32;                          // 20000
    int*   interG   = smask + S_TOT;                      // 32
    int*   unionG   = interG + 32;                        // 32
    int*   ticket   = unionG + 32;                        // 32 (1 used)
    float* hg       = (float*)(ticket + 32);              // 2*32*256
    int*   qcnt     = (int*)(hg + 2 * Q_TOT * H_DIM);     // 32*32
    float* fwt      = (float*)(qcnt + Q_TOT * 32);        // 131*128
    float* w1t      = fwt + FW_LD * D_FUSE;               // 256*64
    float* w2t      = w1t + H_DIM * D_LANG;               // 64*64
    float* wdr      = w2t + D_LANG * D_LANG;              // 128

    k_gi    <<<1026, 768, 0, stream>>>(lang_feat, w_ih, b_ih, fuse_w, sqz_w1, sqz_w2, heat_w,
                                       gi, fwt, w1t, w2t, wdr, qcnt, interG, unionG, ticket);
    k_gru4  <<<Q_TOT * BPQ, GT, 0, stream>>>(gi, w_hh, b_hh, lang_len, hg, qcnt, hbuf);
    k_lang  <<<1, 256, 0, stream>>>(hbuf, w1t, sqz_b1, w2t, sqz_b2, fwt, fuse_b, langc);
    k_fuse  <<<NBLK3, 256, 0, stream>>>(feat, coords, grps, langc, fwt, wdr, heat_b,
                                        grp_part, cnt_part);
    k_argmax<<<Q_TOT, 256, 0, stream>>>(grp_part, cnt_part, best);
    k_smask <<<(S_TOT + 255) / 256, 256, 0, stream>>>(grps, best, smask);
    k_out   <<<1024, 256, 0, stream>>>(supervox, gt, smask, out, interG, unionG, ticket);
}

// Round 6
// 283.783 us; speedup vs baseline: 2.5177x; 1.1331x over previous
//
#include <hip/hip_runtime.h>
#include <hip/hip_bf16.h>
#include <math.h>

#define S_TOT 20000
#define Q_TOT 32
#define N_TOT 200000
#define T_MAX 30
#define G_TOT 64
#define D_IN 300
#define H_DIM 256
#define D_SV 64
#define D_LANG 64
#define D_FUSE 128
#define D_CAT 67
#define FW_LD 131
#define SCHUNK 32
#define NBLK3 (S_TOT / SCHUNK)   // 625
#define SENT64 0xFFFFFFFFFFFFFFFFull

// k_gi GEMM tiling: M=960 (q*30+t), N=768 (j), K=300
#define GI_MT 32
#define GI_NT 64
#define GI_KC 100
#define GI_NB 12   // 768/64
#define GI_GRID (30 * GI_NB)     // 360

__device__ __forceinline__ float sigmoidf_(float x) { return 1.0f / (1.0f + expf(-x)); }
__device__ __forceinline__ unsigned long long pack2(float a, float b) {
    return ((unsigned long long)__float_as_uint(b) << 32) | (unsigned long long)__float_as_uint(a);
}

// ---------------------------------------------------------------- k_gi: gi = x @ W_ih^T + b_ih
// Register-tiled fp32 GEMM. Blocks 0..359: (mb, nb); 360: weight transposes; 361: zeroing.
__global__ __launch_bounds__(128) void k_gi(const float* __restrict__ lang_feat,
                                            const float* __restrict__ w_ih,
                                            const float* __restrict__ b_ih,
                                            const float* __restrict__ fuse_w,
                                            const float* __restrict__ sqz_w1,
                                            const float* __restrict__ sqz_w2,
                                            const float* __restrict__ heat_w,
                                            float* __restrict__ gi,
                                            float* __restrict__ fwt,
                                            float* __restrict__ w1t,
                                            float* __restrict__ w2t,
                                            float* __restrict__ wdr,
                                            int* __restrict__ interG,
                                            int* __restrict__ unionG,
                                            int* __restrict__ ticket) {
    const int tid = threadIdx.x;
    if (blockIdx.x >= GI_GRID) {
        if (blockIdx.x == GI_GRID) {
            for (int i = tid; i < FW_LD * D_FUSE; i += 128)
                fwt[(i % FW_LD) * D_FUSE + (i / FW_LD)] = fuse_w[i];
            for (int i = tid; i < D_LANG * H_DIM; i += 128)
                w1t[(i & 255) * D_LANG + (i >> 8)] = sqz_w1[i];
            for (int i = tid; i < D_LANG * D_LANG; i += 128)
                w2t[(i & 63) * D_LANG + (i >> 6)] = sqz_w2[i];
            if (tid < D_FUSE) wdr[tid] = heat_w[D_FUSE + tid] - heat_w[tid];
        } else {
            if (tid < Q_TOT) { interG[tid] = 0; unionG[tid] = 0; }
            if (tid == 0) *ticket = 0;
        }
        return;
    }
    __shared__ float x_l[GI_KC][GI_MT + 1];
    __shared__ float w_l[GI_KC][GI_NT + 1];
    const int mb = blockIdx.x / GI_NB, nb = blockIdx.x % GI_NB;
    const int m0 = mb * GI_MT, n0 = nb * GI_NT;
    const int tq4 = (tid >> 4) * 4, jq4 = (tid & 15) * 4;

    float acc[4][4];
    #pragma unroll
    for (int i = 0; i < 4; ++i)
        #pragma unroll
        for (int j = 0; j < 4; ++j) acc[i][j] = 0.f;

    for (int kc = 0; kc < 3; ++kc) {
        const int k0 = kc * GI_KC;
        for (int i = tid; i < GI_MT * GI_KC; i += 128) {
            const int r = i / GI_KC, k = i % GI_KC;
            const int row = m0 + r, q = row / T_MAX, t = row - q * T_MAX;
            x_l[k][r] = lang_feat[(q * T_MAX + t) * D_IN + k0 + k];
        }
        for (int i = tid; i < GI_NT * GI_KC; i += 128) {
            const int r = i / GI_KC, k = i % GI_KC;
            w_l[k][r] = w_ih[(n0 + r) * D_IN + k0 + k];
        }
        __syncthreads();
        #pragma unroll 2
        for (int k = 0; k < GI_KC; ++k) {
            const float x0 = x_l[k][tq4 + 0], x1 = x_l[k][tq4 + 1];
            const float x2 = x_l[k][tq4 + 2], x3 = x_l[k][tq4 + 3];
            const float v0 = w_l[k][jq4 + 0], v1 = w_l[k][jq4 + 1];
            const float v2 = w_l[k][jq4 + 2], v3 = w_l[k][jq4 + 3];
            acc[0][0] = fmaf(x0, v0, acc[0][0]); acc[0][1] = fmaf(x0, v1, acc[0][1]);
            acc[0][2] = fmaf(x0, v2, acc[0][2]); acc[0][3] = fmaf(x0, v3, acc[0][3]);
            acc[1][0] = fmaf(x1, v0, acc[1][0]); acc[1][1] = fmaf(x1, v1, acc[1][1]);
            acc[1][2] = fmaf(x1, v2, acc[1][2]); acc[1][3] = fmaf(x1, v3, acc[1][3]);
            acc[2][0] = fmaf(x2, v0, acc[2][0]); acc[2][1] = fmaf(x2, v1, acc[2][1]);
            acc[2][2] = fmaf(x2, v2, acc[2][2]); acc[2][3] = fmaf(x2, v3, acc[2][3]);
            acc[3][0] = fmaf(x3, v0, acc[3][0]); acc[3][1] = fmaf(x3, v1, acc[3][1]);
            acc[3][2] = fmaf(x3, v2, acc[3][2]); acc[3][3] = fmaf(x3, v3, acc[3][3]);
        }
        __syncthreads();
    }
    const float b0 = b_ih[n0 + jq4 + 0], b1 = b_ih[n0 + jq4 + 1];
    const float b2 = b_ih[n0 + jq4 + 2], b3 = b_ih[n0 + jq4 + 3];
    #pragma unroll
    for (int i = 0; i < 4; ++i) {
        const int row = m0 + tq4 + i;
        const int q = row / T_MAX, t = row - q * T_MAX;
        float4 v = make_float4(acc[i][0] + b0, acc[i][1] + b1, acc[i][2] + b2, acc[i][3] + b3);
        *(float4*)&gi[(q * T_MAX + t) * 768 + n0 + jq4] = v;
    }
}

// ---------------------------------------------------------------- cooperative GRU, 8 blocks/query
// 256 blocks (1/CU, all resident). Block (q,b) owns h[b*32..b*32+32); its 96 W_hh rows
// live in LDS (~100 KB). Cross-block h exchange: per-step buffers memset to 0xFF (NaN
// sentinel); producers store u64 pairs (relaxed AGENT), consumers poll the data itself.
__global__ __launch_bounds__(384, 1) void k_gru8(const float* __restrict__ gi,
                                                 const float* __restrict__ w_hh,
                                                 const float* __restrict__ b_hh,
                                                 const int* __restrict__ lang_len,
                                                 float* __restrict__ hg,      // [30][32][256]
                                                 float* __restrict__ hbuf) {  // [32][256]
    __shared__ float wlds[96][260];            // 99840 B, row-pad 4 floats
    __shared__ __align__(16) float hl[H_DIM];
    __shared__ float ghl[96];
    __shared__ float hown[32];
    __shared__ float gil[T_MAX * 96];

    const int tid = threadIdx.x;
    const int q = blockIdx.x >> 3, b = blockIdx.x & 7;
    int len = lang_len[q]; if (len > T_MAX) len = T_MAX; if (len < 1) len = 1;

    // weights into LDS: row r -> W_hh row (r>>5)*256 + b*32 + (r&31)
    for (int i = tid; i < 96 * H_DIM; i += 384) {
        const int r = i >> 8, k = i & 255;
        wlds[r][k] = w_hh[(size_t)(((r >> 5) << 8) + (b << 5) + (r & 31)) * H_DIM + k];
    }
    // gi slices: gil[t*96 + gate*32 + jl]
    for (int i = tid; i < len * 96; i += 384) {
        const int t = i / 96, r = i % 96;
        gil[i] = gi[(q * T_MAX + t) * 768 + ((r >> 5) << 8) + (b << 5) + (r & 31)];
    }
    __syncthreads();

    // step 0: h0 = 0 => gh = b_hh
    if (tid < 32) {
        const float bhr = b_hh[(b << 5) + tid];
        const float bhz = b_hh[H_DIM + (b << 5) + tid];
        const float bhn = b_hh[2 * H_DIM + (b << 5) + tid];
        const float r = sigmoidf_(gil[tid] + bhr);
        const float z = sigmoidf_(gil[32 + tid] + bhz);
        const float n = tanhf(gil[64 + tid] + r * bhn);
        hown[tid] = (1.f - z) * n;
    }
    __syncthreads();
    if (len > 1 && tid < 16) {
        unsigned long long* dst = (unsigned long long*)(hg + q * H_DIM + (b << 5));
        __hip_atomic_store(dst + tid, pack2(hown[2 * tid], hown[2 * tid + 1]),
                           __ATOMIC_RELAXED, __HIP_MEMORY_SCOPE_AGENT);
    }

    const int row = tid >> 2, ql = tid & 3;
    const float bh = b_hh[((row >> 5) << 8) + (b << 5) + (row & 31)];

    for (int t = 1; t < len; ++t) {
        // poll previous-step h (data itself is the ready flag)
        if (tid < 128) {
            const unsigned long long* src =
                (const unsigned long long*)(hg + (size_t)(t - 1) * (Q_TOT * H_DIM) + q * H_DIM);
            unsigned long long v;
            while ((v = __hip_atomic_load(src + tid, __ATOMIC_RELAXED, __HIP_MEMORY_SCOPE_AGENT))
                   == SENT64)
                __builtin_amdgcn_s_sleep(1);
            hl[2 * tid]     = __uint_as_float((unsigned)(v & 0xffffffffu));
            hl[2 * tid + 1] = __uint_as_float((unsigned)(v >> 32));
        }
        __syncthreads();
        // 96 dots x 256, 4 lanes per dot, weights from LDS
        const float4* h4 = (const float4*)(hl + (ql << 6));
        const float4* w4 = (const float4*)(&wlds[row][ql << 6]);
        float ax = 0.f, ay = 0.f, az = 0.f, aw = 0.f;
        #pragma unroll
        for (int i = 0; i < 16; ++i) {
            const float4 wv = w4[i], hv = h4[i];
            ax = fmaf(wv.x, hv.x, ax);
            ay = fmaf(wv.y, hv.y, ay);
            az = fmaf(wv.z, hv.z, az);
            aw = fmaf(wv.w, hv.w, aw);
        }
        float s = (ax + ay) + (az + aw);
        s += __shfl_xor(s, 1);
        s += __shfl_xor(s, 2);
        if (ql == 0) ghl[row] = s + bh;
        __syncthreads();
        if (tid < 32) {
            const float* gt_ = gil + t * 96;
            const float r = sigmoidf_(gt_[tid] + ghl[tid]);
            const float z = sigmoidf_(gt_[32 + tid] + ghl[32 + tid]);
            const float n = tanhf(gt_[64 + tid] + r * ghl[64 + tid]);
            const float hold = hl[(b << 5) + tid];
            hown[tid] = (1.f - z) * n + z * hold;
        }
        __syncthreads();
        if (t < len - 1 && tid < 16) {
            unsigned long long* dst =
                (unsigned long long*)(hg + (size_t)t * (Q_TOT * H_DIM) + q * H_DIM + (b << 5));
            __hip_atomic_store(dst + tid, pack2(hown[2 * tid], hown[2 * tid + 1]),
                               __ATOMIC_RELAXED, __HIP_MEMORY_SCOPE_AGENT);
        }
    }
    if (tid < 32) hbuf[q * H_DIM + (b << 5) + tid] = hown[tid];
}

// ---------------------------------------------------------------- lang head, one block per query
__global__ __launch_bounds__(256) void k_lang(const float* __restrict__ hbuf,
                                              const float* __restrict__ w1t, const float* __restrict__ b1,
                                              const float* __restrict__ w2t, const float* __restrict__ b2,
                                              const float* __restrict__ fwt, const float* __restrict__ fuse_b,
                                              float* __restrict__ langc) {
    __shared__ float hql[H_DIM];
    __shared__ float t1l[D_LANG];
    __shared__ float lgl[D_LANG];
    const int q = blockIdx.x, tid = threadIdx.x;
    hql[tid] = hbuf[q * H_DIM + tid];
    __syncthreads();
    {   // t1 = relu(w1 . h + b1): c = tid>>2, 4 lanes x 64 k
        const int c = tid >> 2, ql = tid & 3;
        float a = 0.f;
        #pragma unroll 8
        for (int j = 0; j < 64; ++j) {
            const int k = (ql << 6) + j;
            a = fmaf(w1t[k * D_LANG + c], hql[k], a);
        }
        a += __shfl_xor(a, 1);
        a += __shfl_xor(a, 2);
        if (ql == 0) t1l[c] = fmaxf(a + b1[c], 0.f);
    }
    __syncthreads();
    {   // lg = w2 . t1 + b2
        const int c = tid >> 2, ql = tid & 3;
        float a = 0.f;
        #pragma unroll
        for (int j = 0; j < 16; ++j) {
            const int k = (ql << 4) + j;
            a = fmaf(w2t[k * D_LANG + c], t1l[k], a);
        }
        a += __shfl_xor(a, 1);
        a += __shfl_xor(a, 2);
        if (ql == 0) lgl[c] = a + b2[c];
    }
    __syncthreads();
    {   // langc = fuse_w[:,67:] . lg + fuse_b
        const int d = tid >> 1, hh = tid & 1;
        float a = 0.f;
        #pragma unroll 8
        for (int j = 0; j < 32; ++j) {
            const int k = (hh << 5) + j;
            a = fmaf(fwt[(D_CAT + k) * D_FUSE + d], lgl[k], a);
        }
        a += __shfl_xor(a, 1);
        if (hh == 0) langc[q * D_FUSE + d] = a + fuse_b[d];
    }
}

// ---------------------------------------------------------------- fused sv_proj + score + group partials
__global__ __launch_bounds__(256) void k_fuse(const float* __restrict__ feat,
                                              const float* __restrict__ coords,
                                              const int* __restrict__ grps,
                                              const float* __restrict__ langc,
                                              const float* __restrict__ fwt,
                                              const float* __restrict__ wdr_g,
                                              const float* __restrict__ heat_b,
                                              float* __restrict__ grp_part,
                                              int* __restrict__ cnt_part) {
    __shared__ __align__(16) float svin[SCHUNK][68];
    __shared__ __align__(16) float svp[SCHUNK][132];
    __shared__ float score[SCHUNK][Q_TOT];
    __shared__ int grps_l[SCHUNK];
    const int tid = threadIdx.x;
    const int s0 = blockIdx.x * SCHUNK;

    const int dsl = tid & 3, q = (tid >> 2) & 31, sg = tid >> 7;
    float lc[32], wdr[32];
    #pragma unroll
    for (int i = 0; i < 32; ++i) {
        const int d = dsl * 32 + i;
        lc[i]  = langc[q * D_FUSE + d];
        wdr[i] = wdr_g[d];
    }
    const float hbd = heat_b[1] - heat_b[0];

    for (int i = tid; i < SCHUNK * D_SV; i += 256) {
        const int r = i >> 6, c = i & 63;
        svin[r][c] = feat[(s0 + r) * D_SV + c];
    }
    if (tid < SCHUNK * 3) { const int r = tid / 3, c = tid % 3; svin[r][D_SV + c] = coords[(s0 + r) * 3 + c]; }
    if (tid < SCHUNK) grps_l[tid] = grps[s0 + tid];
    __syncthreads();

    {
        const int d = tid & 127, sl0 = tid >> 7;
        float acc[16];
        #pragma unroll
        for (int i = 0; i < 16; ++i) acc[i] = 0.f;
        for (int k = 0; k < D_CAT; ++k) {
            const float wv = fwt[k * D_FUSE + d];
            #pragma unroll
            for (int i = 0; i < 16; ++i)
                acc[i] = fmaf(svin[sl0 + 2 * i][k], wv, acc[i]);
        }
        #pragma unroll
        for (int i = 0; i < 16; ++i) svp[sl0 + 2 * i][d] = acc[i];
    }
    __syncthreads();

    for (int si = 0; si < 16; ++si) {
        const int sl = sg * 16 + si;
        const float4* sv4 = (const float4*)(&svp[sl][dsl * 32]);
        float part = 0.f;
        #pragma unroll
        for (int i4 = 0; i4 < 8; ++i4) {
            const float4 v = sv4[i4];
            part = fmaf(fmaxf(v.x + lc[i4*4+0], 0.f), wdr[i4*4+0], part);
            part = fmaf(fmaxf(v.y + lc[i4*4+1], 0.f), wdr[i4*4+1], part);
            part = fmaf(fmaxf(v.z + lc[i4*4+2], 0.f), wdr[i4*4+2], part);
            part = fmaf(fmaxf(v.w + lc[i4*4+3], 0.f), wdr[i4*4+3], part);
        }
        part += __shfl_xor(part, 1);
        part += __shfl_xor(part, 2);
        if (dsl == 0) score[sl][q] = sigmoidf_(part + hbd);
    }
    __syncthreads();

    for (int i = 0; i < 8; ++i) {
        const int cell = tid + 256 * i;            // q*64+g
        const int qq = cell >> 6, g = cell & 63;
        float sum = 0.f;
        #pragma unroll
        for (int sl = 0; sl < SCHUNK; ++sl)
            sum += (grps_l[sl] == g) ? score[sl][qq] : 0.f;
        grp_part[blockIdx.x * (Q_TOT * G_TOT) + cell] = sum;
        if (cell < G_TOT) {
            int c = 0;
            #pragma unroll
            for (int sl = 0; sl < SCHUNK; ++sl) c += (grps_l[sl] == g);
            cnt_part[blockIdx.x * G_TOT + g] = c;
        }
    }
}

// ---------------------------------------------------------------- reduce partials + argmax per q
__global__ __launch_bounds__(256) void k_argmax(const float* __restrict__ grp_part,
                                                const int* __restrict__ cnt_part,
                                                int* __restrict__ best) {
    __shared__ float ps[4][G_TOT];
    __shared__ int   pc[4][G_TOT];
    __shared__ float sc[G_TOT];
    const int q = blockIdx.x, tid = threadIdx.x;
    const int bq = tid >> 6, g = tid & 63;
    float acc = 0.f; int cacc = 0;
    for (int b = bq; b < NBLK3; b += 4) {
        acc  += grp_part[b * (Q_TOT * G_TOT) + q * G_TOT + g];
        cacc += cnt_part[b * G_TOT + g];
    }
    ps[bq][g] = acc; pc[bq][g] = cacc;
    __syncthreads();
    if (tid < G_TOT) {
        const float s = ((ps[0][tid] + ps[1][tid]) + ps[2][tid]) + ps[3][tid];
        const int   c = ((pc[0][tid] + pc[1][tid]) + pc[2][tid]) + pc[3][tid];
        sc[tid] = s / (float)c;
    }
    __syncthreads();
    if (tid == 0) {
        float bv = sc[0]; int bi = 0;
        for (int g2 = 1; g2 < G_TOT; ++g2) if (sc[g2] > bv) { bv = sc[g2]; bi = g2; }
        best[q] = bi;
    }
}

// ---------------------------------------------------------------- smask[s] = bitmask over q
__global__ __launch_bounds__(256) void k_smask(const int* __restrict__ grps,
                                               const int* __restrict__ best,
                                               int* __restrict__ smask) {
    const int s = blockIdx.x * 256 + threadIdx.x;
    if (s >= S_TOT) return;
    const int g = grps[s];
    int m = 0;
    #pragma unroll
    for (int qq = 0; qq < Q_TOT; ++qq) m |= (best[qq] == g) ? (1 << qq) : 0;
    smask[s] = m;
}

// ---------------------------------------------------------------- obj_pts + inter/union + iou (ticketed)
__global__ __launch_bounds__(256) void k_out(const int* __restrict__ supervox,
                                             const int* __restrict__ gt,
                                             const int* __restrict__ smask,
                                             float* __restrict__ out,
                                             int* __restrict__ interG, int* __restrict__ unionG,
                                             int* __restrict__ ticket) {
    const int tid = threadIdx.x;
    const int gidx = blockIdx.x * 256 + tid;
    const int q = gidx & 31;
    const int nstride = (gridDim.x * 256) >> 5;
    int ai = 0, au = 0;
    for (int n = gidx >> 5; n < N_TOT; n += nstride) {
        const int m = smask[supervox[n]];
        const int o = (m >> q) & 1;
        const int g = gt[n * Q_TOT + q];
        out[n * Q_TOT + q] = (float)o;
        ai += o & g; au += o | g;
    }
    __shared__ int bi[Q_TOT], bu[Q_TOT];
    __shared__ int islast;
    if (tid < Q_TOT) { bi[tid] = 0; bu[tid] = 0; }
    __syncthreads();
    atomicAdd(&bi[q], ai); atomicAdd(&bu[q], au);
    __syncthreads();
    if (tid < Q_TOT) { atomicAdd(&interG[tid], bi[tid]); atomicAdd(&unionG[tid], bu[tid]); }
    asm volatile("s_waitcnt vmcnt(0)" ::: "memory");
    if (tid == 0) {
        const int old = __hip_atomic_fetch_add(ticket, 1, __ATOMIC_RELAXED, __HIP_MEMORY_SCOPE_AGENT);
        islast = (old == (int)gridDim.x - 1) ? 1 : 0;
    }
    __syncthreads();
    if (islast && tid < Q_TOT) {
        const int iv = __hip_atomic_load(&interG[tid], __ATOMIC_RELAXED, __HIP_MEMORY_SCOPE_AGENT);
        const int uv = __hip_atomic_load(&unionG[tid], __ATOMIC_RELAXED, __HIP_MEMORY_SCOPE_AGENT);
        out[(size_t)N_TOT * Q_TOT + tid] = (float)iv / ((float)uv + 1e-5f);
    }
}

extern "C" void kernel_launch(void* const* d_in, const int* in_sizes, int n_in,
                              void* d_out, int out_size, void* d_ws, size_t ws_size,
                              hipStream_t stream) {
    const float* lang_feat = (const float*)d_in[0];
    const float* feat      = (const float*)d_in[1];
    const float* coords    = (const float*)d_in[2];
    const int*   lang_len  = (const int*)d_in[3];
    const int*   grps      = (const int*)d_in[4];
    const int*   supervox  = (const int*)d_in[5];
    const int*   gt        = (const int*)d_in[6];
    const float* w_ih      = (const float*)d_in[7];
    const float* w_hh      = (const float*)d_in[8];
    const float* b_ih      = (const float*)d_in[9];
    const float* b_hh      = (const float*)d_in[10];
    const float* sqz_w1    = (const float*)d_in[11];
    const float* sqz_b1    = (const float*)d_in[12];
    const float* sqz_w2    = (const float*)d_in[13];
    const float* sqz_b2    = (const float*)d_in[14];
    const float* fuse_w    = (const float*)d_in[15];
    const float* fuse_b    = (const float*)d_in[16];
    const float* heat_w    = (const float*)d_in[17];
    const float* heat_b    = (const float*)d_in[18];
    float* out = (float*)d_out;

    float* gi       = (float*)d_ws;                       // 737280
    float* hbuf     = gi + 737280;                        // 8192
    float* langc    = hbuf + 8192;                        // 4096
    float* grp_part = langc + 4096;                       // 625*2048
    int*   cnt_part = (int*)(grp_part + NBLK3 * 2048);    // 625*64
    int*   best     = cnt_part + NBLK3 * 64;              // 32
    int*   smask    = best + 32;                          // 20000
    int*   interG   = smask + S_TOT;                      // 32
    int*   unionG   = interG + 32;                        // 32
    int*   ticket   = unionG + 32;                        // 32 (1 used)
    float* hg       = (float*)(ticket + 32);              // 30*32*256
    float* fwt      = hg + 30 * Q_TOT * H_DIM;            // 131*128
    float* w1t      = fwt + FW_LD * D_FUSE;               // 256*64
    float* w2t      = w1t + H_DIM * D_LANG;               // 64*64
    float* wdr      = w2t + D_LANG * D_LANG;              // 128

    // sentinel-fill the per-step h buffers (0xFF bytes = NaN pattern no computed h equals)
    hipMemsetAsync(hg, 0xFF, (size_t)30 * Q_TOT * H_DIM * sizeof(float), stream);

    k_gi    <<<GI_GRID + 2, 128, 0, stream>>>(lang_feat, w_ih, b_ih, fuse_w, sqz_w1, sqz_w2, heat_w,
                                              gi, fwt, w1t, w2t, wdr, interG, unionG, ticket);
    k_gru8  <<<Q_TOT * 8, 384, 0, stream>>>(gi, w_hh, b_hh, lang_len, hg, hbuf);
    k_lang  <<<Q_TOT, 256, 0, stream>>>(hbuf, w1t, sqz_b1, w2t, sqz_b2, fwt, fuse_b, langc);
    k_fuse  <<<NBLK3, 256, 0, stream>>>(feat, coords, grps, langc, fwt, wdr, heat_b,
                                        grp_part, cnt_part);
    k_argmax<<<Q_TOT, 256, 0, stream>>>(grp_part, cnt_part, best);
    k_smask <<<(S_TOT + 255) / 256, 256, 0, stream>>>(grps, best, smask);
    k_out   <<<1024, 256, 0, stream>>>(supervox, gt, smask, out, interG, unionG, ticket);
}